// Round 4
// baseline (1573.184 us; speedup 1.0000x reference)
//
#include <hip/hip_runtime.h>
#include <cstdint>

#define HID 4096
#define SEQ 1024
#define B_REQ 4
#define NH 32
#define DH 128
#define RANK 16

typedef unsigned short u16;
typedef __attribute__((ext_vector_type(8))) short short8;
typedef __attribute__((ext_vector_type(8))) unsigned short us8;
typedef __attribute__((ext_vector_type(4))) float f32x4;

static __device__ __forceinline__ float bf2f(u16 u) {
  union { unsigned int i; float f; } v; v.i = ((unsigned int)u) << 16; return v.f;
}
static __device__ __forceinline__ u16 f2bf(float f) {
  union { float f; unsigned int i; } v; v.f = f;
  unsigned int r = v.i + 0x7FFFu + ((v.i >> 16) & 1u);  // RNE
  return (u16)(r >> 16);
}

template<typename T> struct io;
template<> struct io<u16> {
  static __device__ __forceinline__ float ld(const u16* p, size_t i) { return bf2f(p[i]); }
  static __device__ __forceinline__ void st(u16* p, size_t i, float v) { p[i] = f2bf(v); }
};
template<> struct io<float> {
  static __device__ __forceinline__ float ld(const float* p, size_t i) { return p[i]; }
  static __device__ __forceinline__ void st(float* p, size_t i, float v) { p[i] = v; }
};

static __device__ __forceinline__ void ld8f(const u16* p, float* o) {
  us8 v = *(const us8*)p;
#pragma unroll
  for (int i = 0; i < 8; i++) o[i] = bf2f(v[i]);
}
static __device__ __forceinline__ void ld8f(const float* p, float* o) {
  const float4* q = (const float4*)p;
  float4 a = q[0], b = q[1];
  o[0]=a.x; o[1]=a.y; o[2]=a.z; o[3]=a.w; o[4]=b.x; o[5]=b.y; o[6]=b.z; o[7]=b.w;
}

// ---------- dtype probe: bf16 weights never have exponent >= 0xC0; fp32 low halves do ----------
__global__ void detect_k(const u16* __restrict__ w, int* __restrict__ dflag) {
  if (threadIdx.x == 0 && blockIdx.x == 0) {
    int huge = 0;
    for (int i = 0; i < 2048; i++) {
      int e = (w[i] >> 7) & 0xFF;
      if (e >= 0xC0) huge++;
    }
    dflag[0] = (huge > 8) ? 1 : 0;   // 1 => inputs are float32
  }
}

// ---------- convert input matrix to bf16 (identity when already bf16) ----------
template<typename T>
__global__ __launch_bounds__(256) void convert_k(const int* __restrict__ fl, int want,
    const T* __restrict__ src, u16* __restrict__ dst, int n) {
  if (fl[0] != want) return;
  int stride = gridDim.x * blockDim.x;
  for (int i = blockIdx.x * blockDim.x + threadIdx.x; i < n; i += stride)
    dst[i] = f2bf(io<T>::ld(src, i));
}

// ---------- transpose 4096x4096: T[n][k] = bf16(W[k][n]) ----------
template<typename T>
__global__ __launch_bounds__(256) void transpose_k(const int* __restrict__ fl, int want,
    const T* __restrict__ W, u16* __restrict__ Tt) {
  if (fl[0] != want) return;
  __shared__ u16 st[64][68];
  int r0 = blockIdx.y * 64, c0 = blockIdx.x * 64;
  int t = threadIdx.x;
  int r = t >> 2, cb = (t & 3) * 16;
#pragma unroll
  for (int j = 0; j < 16; j++)
    st[r][cb + j] = f2bf(io<T>::ld(W, (size_t)(r0 + r) * HID + c0 + cb + j));
  __syncthreads();
#pragma unroll
  for (int j = 0; j < 4; j++) {
    int cw = cb + j*4;
    ushort4 v;
    v.x = st[cw+0][r]; v.y = st[cw+1][r]; v.z = st[cw+2][r]; v.w = st[cw+3][r];
    *(ushort4*)&Tt[(size_t)(c0 + r) * HID + r0 + cw] = v;
  }
}

// ---------- A^T prep: AT[mat][j][d] = bf16(A_tens[b][d][j]), mat = tens*4+b ----------
// A row d is 16 contiguous values -> per-thread 64B contiguous read; write coalesced across t.
template<typename T>
__global__ __launch_bounds__(256) void at_trans_k(const int* __restrict__ fl, int want,
    const T* __restrict__ A0, const T* __restrict__ A1, const T* __restrict__ A2,
    const T* __restrict__ A3, u16* __restrict__ AT) {
  if (fl[0] != want) return;
  int mat = blockIdx.y;
  int tens = mat >> 2, b = mat & 3;
  const T* src = (tens==0?A0: tens==1?A1: tens==2?A2:A3) + (size_t)b * HID * RANK;
  int d = blockIdx.x * 256 + threadIdx.x;
  float v[RANK];
#pragma unroll
  for (int q = 0; q < RANK; q++) v[q] = io<T>::ld(src, (size_t)d * RANK + q);
  u16* dst = AT + (size_t)mat * RANK * HID;
#pragma unroll
  for (int q = 0; q < RANK; q++) dst[(size_t)q * HID + d] = f2bf(v[q]);
}

// ---------- r[m,b,s,:] = x_row @ A  via pre-transposed AT (bf16). ----------
// block = 16 s x 16 j; thread (sg=t>>4, j=t&15) owns one output: two row-reads, no LDS,
// no reduction. x us8 broadcasts across the 16 j-lanes; AT rows coalesce per quad.
__global__ __launch_bounds__(256) void lora_r_k(
    const u16* __restrict__ X, const u16* __restrict__ AT, float* __restrict__ R) {
  int st = blockIdx.x, b = blockIdx.y, m = blockIdx.z;
  int t = threadIdx.x;
  int j = t & 15, sg = t >> 4;
  int s = st * 16 + sg;
  int mat = m * B_REQ + b;
  const u16* xp = X + (size_t)(b * SEQ + s) * HID;
  const u16* ap = AT + ((size_t)mat * RANK + j) * HID;
  float acc = 0.f;
#pragma unroll 4
  for (int i = 0; i < HID / 8; i++) {
    us8 xv = *(const us8*)(xp + i * 8);
    us8 av = *(const us8*)(ap + i * 8);
#pragma unroll
    for (int q = 0; q < 8; q++) acc += bf2f(xv[q]) * bf2f(av[q]);
  }
  R[((size_t)(m * B_REQ + b) * SEQ + s) * RANK + j] = acc;
}

// ================= 256x256 8-phase GEMM: C = A @ BT^T (m201 template, plain HIP) ==========
#define GMFMA __builtin_amdgcn_mfma_f32_16x16x32_bf16
#define WAITV4 asm volatile("s_waitcnt vmcnt(4)" ::: "memory")
#define WAITV0 asm volatile("s_waitcnt vmcnt(0)" ::: "memory")
#define WAITL0 asm volatile("s_waitcnt lgkmcnt(0)" ::: "memory")
#define SBAR   __builtin_amdgcn_s_barrier()
#define SCHED0 __builtin_amdgcn_sched_barrier(0)

#define LDA(BUF,QM,MF,KH) \
  (*(const short8*)((const char*)(&lds[BUF][0][0]) + \
     (((QM)*128 + wm*64 + (MF)*16 + l15) * 128) + (((KH)*64 + quad*16) ^ ((l15 & 7) << 4))))
#define LDB(BUF,QN,NF,KH) \
  (*(const short8*)((const char*)(&lds[BUF][1][0]) + \
     (((QN)*128 + wn*32 + (NF)*16 + l15) * 128) + (((KH)*64 + quad*16) ^ ((l15 & 7) << 4))))

#define MFMA_BLK(QM,QN,A0,A1,A2,A3,B0,B1) \
    acc[(QM)*4+0][(QN)*2+0] = GMFMA(A0,B0,acc[(QM)*4+0][(QN)*2+0],0,0,0); \
    acc[(QM)*4+1][(QN)*2+0] = GMFMA(A1,B0,acc[(QM)*4+1][(QN)*2+0],0,0,0); \
    acc[(QM)*4+2][(QN)*2+0] = GMFMA(A2,B0,acc[(QM)*4+2][(QN)*2+0],0,0,0); \
    acc[(QM)*4+3][(QN)*2+0] = GMFMA(A3,B0,acc[(QM)*4+3][(QN)*2+0],0,0,0); \
    acc[(QM)*4+0][(QN)*2+1] = GMFMA(A0,B1,acc[(QM)*4+0][(QN)*2+1],0,0,0); \
    acc[(QM)*4+1][(QN)*2+1] = GMFMA(A1,B1,acc[(QM)*4+1][(QN)*2+1],0,0,0); \
    acc[(QM)*4+2][(QN)*2+1] = GMFMA(A2,B1,acc[(QM)*4+2][(QN)*2+1],0,0,0); \
    acc[(QM)*4+3][(QN)*2+1] = GMFMA(A3,B1,acc[(QM)*4+3][(QN)*2+1],0,0,0);

#define PHASE(BUF, QM, QN, STAGE) do { \
    short8 a00=LDA(BUF,QM,0,0), a10=LDA(BUF,QM,1,0), a20=LDA(BUF,QM,2,0), a30=LDA(BUF,QM,3,0); \
    short8 a01=LDA(BUF,QM,0,1), a11=LDA(BUF,QM,1,1), a21=LDA(BUF,QM,2,1), a31=LDA(BUF,QM,3,1); \
    short8 b00=LDB(BUF,QN,0,0), b10=LDB(BUF,QN,1,0); \
    short8 b01=LDB(BUF,QN,0,1), b11=LDB(BUF,QN,1,1); \
    STAGE; \
    WAITV4; SCHED0; \
    SBAR; \
    WAITL0; SCHED0; \
    __builtin_amdgcn_s_setprio(1); \
    MFMA_BLK(QM,QN,a00,a10,a20,a30,b00,b10) \
    MFMA_BLK(QM,QN,a01,a11,a21,a31,b01,b11) \
    __builtin_amdgcn_s_setprio(0); \
    SBAR; \
  } while (0)

#define PHASE_TAIL(BUF, QM, QN) do { \
    short8 a00=LDA(BUF,QM,0,0), a10=LDA(BUF,QM,1,0), a20=LDA(BUF,QM,2,0), a30=LDA(BUF,QM,3,0); \
    short8 a01=LDA(BUF,QM,0,1), a11=LDA(BUF,QM,1,1), a21=LDA(BUF,QM,2,1), a31=LDA(BUF,QM,3,1); \
    short8 b00=LDB(BUF,QN,0,0), b10=LDB(BUF,QN,1,0); \
    short8 b01=LDB(BUF,QN,0,1), b11=LDB(BUF,QN,1,1); \
    WAITL0; SCHED0; \
    __builtin_amdgcn_s_setprio(1); \
    MFMA_BLK(QM,QN,a00,a10,a20,a30,b00,b10) \
    MFMA_BLK(QM,QN,a01,a11,a21,a31,b01,b11) \
    __builtin_amdgcn_s_setprio(0); \
  } while (0)

template<typename TOUT>
__global__ __launch_bounds__(512, 2) void gemm256_k(const int* __restrict__ fl, int want,
    const u16* __restrict__ A, const u16* __restrict__ BT, TOUT* __restrict__ C) {
  if (want >= 0 && fl[0] != want) return;
  __shared__ u16 lds[2][2][256*64];     // [buf][A/B][row*64], 128 KiB
  const int tid = threadIdx.x, lane = tid & 63, wave = tid >> 6;
  const int l15 = lane & 15, quad = lane >> 4;
  const int wm = wave >> 2, wn = wave & 3;
  int bid = blockIdx.x;
  int swz = (bid & 7) * 32 + (bid >> 3);
  const int m0 = (swz >> 4) * 256, n0 = (swz & 15) * 256;
  const int r = tid >> 3;                                    // 0..63 row within issue
  const int ce = ((((tid & 7) * 16) ^ ((r & 7) << 4)) >> 1); // logical elem col 0..63

  auto stA = [&](int nb, int ht, int kt) {
    const u16* s0 = A + (size_t)(m0 + ht*64 + r)       * HID + kt*64 + ce;
    const u16* s1 = A + (size_t)(m0 + 128 + ht*64 + r) * HID + kt*64 + ce;
    u16* d0 = &lds[nb][0][(ht*128 + wave*8) * 64];
    u16* d1 = &lds[nb][0][(ht*128 + 64 + wave*8) * 64];
    __builtin_amdgcn_global_load_lds((const __attribute__((address_space(1))) void*)s0,
        (__attribute__((address_space(3))) void*)d0, 16, 0, 0);
    __builtin_amdgcn_global_load_lds((const __attribute__((address_space(1))) void*)s1,
        (__attribute__((address_space(3))) void*)d1, 16, 0, 0);
  };
  auto stB = [&](int nb, int qn, int kt) {
    const u16* s0 = BT + (size_t)(n0 + (r>>5)*64 + qn*32 + (r&31))       * HID + kt*64 + ce;
    const u16* s1 = BT + (size_t)(n0 + 128 + (r>>5)*64 + qn*32 + (r&31)) * HID + kt*64 + ce;
    u16* d0 = &lds[nb][1][(qn*128 + wave*8) * 64];
    u16* d1 = &lds[nb][1][(qn*128 + 64 + wave*8) * 64];
    __builtin_amdgcn_global_load_lds((const __attribute__((address_space(1))) void*)s0,
        (__attribute__((address_space(3))) void*)d0, 16, 0, 0);
    __builtin_amdgcn_global_load_lds((const __attribute__((address_space(1))) void*)s1,
        (__attribute__((address_space(3))) void*)d1, 16, 0, 0);
  };

  f32x4 acc[8][4];
  f32x4 zero = {0.f,0.f,0.f,0.f};
#pragma unroll
  for (int i=0;i<8;i++)
#pragma unroll
    for (int j=0;j<4;j++) acc[i][j] = zero;

  stA(0,0,0); stB(0,0,0); stA(0,1,0); stB(0,1,0);
  WAITV4; SCHED0;
  SBAR;

  for (int tt = 0; tt < 31; ++tt) {
    int kn = tt*2 + 1;
    PHASE(0,0,0, stA(1,0,kn)); PHASE(0,1,0, stB(1,0,kn));
    PHASE(0,0,1, stA(1,1,kn)); PHASE(0,1,1, stB(1,1,kn));
    PHASE(1,0,0, stA(0,0,kn+1)); PHASE(1,1,0, stB(0,0,kn+1));
    PHASE(1,0,1, stA(0,1,kn+1)); PHASE(1,1,1, stB(0,1,kn+1));
  }
  PHASE(0,0,0, stA(1,0,63)); PHASE(0,1,0, stB(1,0,63));
  PHASE(0,0,1, stA(1,1,63)); PHASE(0,1,1, stB(1,1,63));
  WAITV0; SCHED0;
  SBAR;
  PHASE_TAIL(1,0,0); PHASE_TAIL(1,1,0); PHASE_TAIL(1,0,1); PHASE_TAIL(1,1,1);

  const int crow = m0 + wm*128 + quad*4;
  const int ccol = n0 + wn*64 + l15;
#pragma unroll
  for (int mfi = 0; mfi < 8; mfi++)
#pragma unroll
    for (int nfi = 0; nfi < 4; nfi++)
#pragma unroll
      for (int rr = 0; rr < 4; rr++)
        io<TOUT>::st(C, (size_t)(crow + (mfi>>2)*64 + (mfi&3)*16 + rr) * HID
                        + ccol + (nfi>>1)*32 + (nfi&1)*16, acc[mfi][nfi][rr]);
}

// ---------- in-place bf16: val = lin + r@B ; rope for kind 0,1 ; plain for kind 2 ----------
template<typename T>
__global__ __launch_bounds__(256) void lora_rope_k(const int* __restrict__ fl, int want,
    u16* __restrict__ Qb, u16* __restrict__ Kb, u16* __restrict__ Vb,
    const float* __restrict__ R,
    const T* __restrict__ Bq, const T* __restrict__ Bk, const T* __restrict__ Bv) {
  if (fl[0] != want) return;
  int s0 = blockIdx.x * 4;
  int z = blockIdx.y; int kind = z >> 2, b = z & 3;
  u16* Ob = kind==0?Qb: kind==1?Kb:Vb;
  const T* Bm = (kind==0?Bq: kind==1?Bk:Bv) + (size_t)b * RANK * HID;
  int t = threadIdx.x;
  int h = t >> 3, d0 = (t & 7) * 8;
  int col0 = h*DH + d0, col1 = col0 + 64;
  __shared__ float rr[4][RANK];
  if (t < 64)
    rr[t>>4][t&15] = R[((size_t)(kind*B_REQ + b) * SEQ + s0 + (t>>4)) * RANK + (t&15)];
  __syncthreads();
  float v0[4][8], v1[4][8];
  size_t base = (size_t)(b*SEQ + s0) * HID;
#pragma unroll
  for (int si = 0; si < 4; si++) {
    us8 a = *(const us8*)&Ob[base + (size_t)si*HID + col0];
    us8 c = *(const us8*)&Ob[base + (size_t)si*HID + col1];
#pragma unroll
    for (int i = 0; i < 8; i++) { v0[si][i] = bf2f(a[i]); v1[si][i] = bf2f(c[i]); }
  }
#pragma unroll 4
  for (int j = 0; j < RANK; j++) {
    float b0[8], b1[8];
    ld8f(Bm + (size_t)j*HID + col0, b0);
    ld8f(Bm + (size_t)j*HID + col1, b1);
#pragma unroll
    for (int si = 0; si < 4; si++) {
      float rj = rr[si][j];
#pragma unroll
      for (int i = 0; i < 8; i++) { v0[si][i] += rj*b0[i]; v1[si][i] += rj*b1[i]; }
    }
  }
  if (kind == 2) {
#pragma unroll
    for (int si = 0; si < 4; si++) {
      us8 a, c;
#pragma unroll
      for (int i = 0; i < 8; i++) { a[i] = f2bf(v0[si][i]); c[i] = f2bf(v1[si][i]); }
      *(us8*)&Ob[base + (size_t)si*HID + col0] = a;
      *(us8*)&Ob[base + (size_t)si*HID + col1] = c;
    }
    return;
  }
  float fr[8];
#pragma unroll
  for (int i = 0; i < 8; i++)
    fr[i] = exp2f((float)(d0 + i) * (-13.287712379549449f / 64.f));
#pragma unroll
  for (int si = 0; si < 4; si++) {
    float sa = (float)(s0 + si);
    us8 a, c;
#pragma unroll
    for (int i = 0; i < 8; i++) {
      float sn, cs;
      sincosf(sa * fr[i], &sn, &cs);
      a[i] = f2bf(v0[si][i]*cs - v1[si][i]*sn);
      c[i] = f2bf(v1[si][i]*cs + v0[si][i]*sn);
    }
    *(us8*)&Ob[base + (size_t)si*HID + col0] = a;
    *(us8*)&Ob[base + (size_t)si*HID + col1] = c;
  }
}

// ---------- V^T: VT[(b*NH+h)*DH + d][s] = V[b*SEQ+s][h*DH+d] ----------
__global__ __launch_bounds__(256) void vtrans_k(const u16* __restrict__ V, u16* __restrict__ VT) {
  int st = blockIdx.x, h = blockIdx.y, b = blockIdx.z;
  int s0 = st * 64;
  __shared__ u16 tmp[64][136];
  int t = threadIdx.x;
  int sr = t >> 2, c0 = (t & 3) * 32;
  const u16* vp = V + (size_t)(b*SEQ + s0 + sr) * HID + h*DH + c0;
#pragma unroll
  for (int j = 0; j < 4; j++)
    *(us8*)&tmp[sr][c0 + j*8] = *(const us8*)(vp + j*8);
  __syncthreads();
  int d = t >> 1, so = (t & 1) * 32;
  u16* op = VT + ((size_t)(b*NH + h) * DH + d) * SEQ + s0 + so;
#pragma unroll
  for (int j = 0; j < 4; j++) {
    us8 v;
#pragma unroll
    for (int i = 0; i < 8; i++) ((u16*)&v)[i] = tmp[so + j*8 + i][d];
    *(us8*)(op + j*8) = v;
  }
}

// ---------- flash attention: block = (b, h, 64 q rows), 4 waves x 16 q rows, KVBLK=64 ----------
__global__ __launch_bounds__(256) void attn_k(
    const u16* __restrict__ Q, const u16* __restrict__ K, const u16* __restrict__ VT,
    u16* __restrict__ O) {
  int qb = (int)gridDim.x - 1 - (int)blockIdx.x;
  int h = blockIdx.y, b = blockIdx.z;
  int q0 = qb * 64;
  int tid = threadIdx.x, lane = tid & 63, wave = tid >> 6;
  int l15 = lane & 15, quad = lane >> 4;
  __shared__ u16 sK[64*136];
  __shared__ u16 sVT[128*72];
  __shared__ u16 sP[4][16*72];
  short8 qf[4];
  {
    const u16* qp = Q + (size_t)(b*SEQ + q0 + wave*16 + l15) * HID + h*DH + quad*8;
#pragma unroll
    for (int c = 0; c < 4; c++) qf[c] = *(const short8*)(qp + c*32);
  }
  f32x4 zero = {0.f,0.f,0.f,0.f};
  f32x4 oacc[8];
#pragma unroll
  for (int i=0;i<8;i++) oacc[i] = zero;
  float m_i[4], l_i[4];
#pragma unroll
  for (int r=0;r<4;r++){ m_i[r] = -1e30f; l_i[r] = 0.f; }
  int krow = tid >> 2, kcol = (tid & 3) * 32;
  int vrow = tid >> 1, vcol = (tid & 1) * 32;
  const u16* kbase = K + (size_t)(b*SEQ) * HID + h*DH;
  const u16* vbase = VT + (size_t)(b*NH + h) * DH * SEQ;
  int nkt = qb + 1;
  for (int kt = 0; kt < nkt; kt++) {
    int k0 = kt * 64;
    __syncthreads();
    {
      const u16* kp = kbase + (size_t)(k0 + krow) * HID + kcol;
#pragma unroll
      for (int j = 0; j < 4; j++)
        *(us8*)&sK[krow*136 + kcol + j*8] = *(const us8*)(kp + j*8);
      const u16* vp = vbase + (size_t)vrow * SEQ + k0 + vcol;
#pragma unroll
      for (int j = 0; j < 4; j++)
        *(us8*)&sVT[vrow*72 + vcol + j*8] = *(const us8*)(vp + j*8);
    }
    __syncthreads();
    int q_hi = q0 + wave*16 + 15;
    if (k0 <= q_hi) {
      f32x4 sc4[4];
#pragma unroll
      for (int g=0;g<4;g++) sc4[g] = zero;
#pragma unroll
      for (int c = 0; c < 4; c++) {
#pragma unroll
        for (int g = 0; g < 4; g++) {
          short8 kf = *(const short8*)&sK[(g*16 + l15)*136 + c*32 + quad*8];
          sc4[g] = __builtin_amdgcn_mfma_f32_16x16x32_bf16(qf[c], kf, sc4[g], 0,0,0);
        }
      }
      const float scale = 0.08838834764831845f;   // 1/sqrt(128)
      float alpha[4], pst[4][4];
#pragma unroll
      for (int r = 0; r < 4; r++) {
        int q_abs = q0 + wave*16 + quad*4 + r;
        float v[4];
#pragma unroll
        for (int g = 0; g < 4; g++) {
          v[g] = sc4[g][r] * scale;
          if (k0 + g*16 + l15 > q_abs) v[g] = -1e30f;
        }
        float mx = fmaxf(fmaxf(v[0],v[1]), fmaxf(v[2],v[3]));
#pragma unroll
        for (int sh = 1; sh < 16; sh <<= 1) mx = fmaxf(mx, __shfl_xor(mx, sh, 64));
        float mnew = fmaxf(m_i[r], mx);
        float a = __expf(m_i[r] - mnew);
        float rs = 0.f;
#pragma unroll
        for (int g = 0; g < 4; g++) { float p = __expf(v[g] - mnew); pst[g][r] = p; rs += p; }
#pragma unroll
        for (int sh = 1; sh < 16; sh <<= 1) rs += __shfl_xor(rs, sh, 64);
        l_i[r] = a * l_i[r] + rs;
        m_i[r] = mnew;
        alpha[r] = a;
      }
#pragma unroll
      for (int dt=0; dt<8; dt++)
#pragma unroll
        for (int r=0;r<4;r++) oacc[dt][r] *= alpha[r];
#pragma unroll
      for (int g = 0; g < 4; g++)
#pragma unroll
        for (int r = 0; r < 4; r++)
          sP[wave][(quad*4+r)*72 + g*16 + l15] = f2bf(pst[g][r]);
      asm volatile("s_waitcnt lgkmcnt(0)" ::: "memory");
      short8 pf0 = *(const short8*)&sP[wave][l15*72 + quad*8];
      short8 pf1 = *(const short8*)&sP[wave][l15*72 + 32 + quad*8];
#pragma unroll
      for (int dt = 0; dt < 8; dt++) {
        short8 vf0 = *(const short8*)&sVT[(dt*16 + l15)*72 + quad*8];
        short8 vf1 = *(const short8*)&sVT[(dt*16 + l15)*72 + 32 + quad*8];
        oacc[dt] = __builtin_amdgcn_mfma_f32_16x16x32_bf16(pf0, vf0, oacc[dt], 0,0,0);
        oacc[dt] = __builtin_amdgcn_mfma_f32_16x16x32_bf16(pf1, vf1, oacc[dt], 0,0,0);
      }
    }
  }
  u16* op = O + (size_t)(b*SEQ + q0 + wave*16 + quad*4) * HID + h*DH + l15;
#pragma unroll
  for (int dt=0; dt<8; dt++)
#pragma unroll
    for (int r=0;r<4;r++) {
      float v = oacc[dt][r] / l_i[r];
      op[(size_t)r * HID + dt*16] = f2bf(v);
    }
}

// ---------- in-place: Out += r_o @ Bo ----------
template<typename T>
__global__ __launch_bounds__(256) void out_add_k(const int* __restrict__ fl, int want,
    const float* __restrict__ Ro, const T* __restrict__ Bo, T* __restrict__ Out) {
  if (fl[0] != want) return;
  int c = blockIdx.x * 256 + threadIdx.x;
  int s = blockIdx.y, b = blockIdx.z;
  __shared__ float rr[RANK];
  if (threadIdx.x < RANK) rr[threadIdx.x] = Ro[((size_t)(b*SEQ + s)) * RANK + threadIdx.x];
  __syncthreads();
  size_t row = (size_t)(b*SEQ + s);
  float val = io<T>::ld(Out, row*HID + c);
  const T* bo = Bo + (size_t)b * RANK * HID;
#pragma unroll
  for (int j = 0; j < RANK; j++) val += rr[j] * io<T>::ld(bo, (size_t)j*HID + c);
  io<T>::st(Out, row*HID + c, val);
}

extern "C" void kernel_launch(void* const* d_in, const int* in_sizes, int n_in,
                              void* d_out, int out_size, void* d_ws, size_t ws_size,
                              hipStream_t stream) {
  char* ws = (char*)d_ws;
  const size_t MAT = (size_t)4096 * 4096 * 2;   // one bf16 4096^2 matrix (32 MB)
  u16* slot0 = (u16*)(ws + 0*MAT);              // W^T staging, then attention output
  u16* slot1 = (u16*)(ws + 1*MAT);              // ATqkv (1.5MB), then k_lin, then Wo^T
  u16* slot2 = (u16*)(ws + 2*MAT);              // v_lin
  u16* X_bf  = (u16*)(ws + 3*MAT);              // bf16 hidden_states, then V^T
  float* r_all = (float*)(ws + 4*MAT);                                  // 768 KB
  float* r_o   = (float*)(ws + 4*MAT + (size_t)3*B_REQ*SEQ*RANK*sizeof(float)); // 256 KB
  int* dflag   = (int*)(ws + 4*MAT + (size_t)4*B_REQ*SEQ*RANK*sizeof(float));   // 4 B
  u16* ATo     = (u16*)(ws + 4*MAT + 1052672);  // 512 KB durable (survives until r_o)
  u16* ATqkv   = slot1;                          // 1.5 MB, dead once k_lin is written

  u16* q_lin = (u16*)d_out;   // scratch until the O-proj GEMM rewrites d_out
  u16* k_lin = slot1;
  u16* v_lin = slot2;
  u16* attnb = slot0;

  const int NX = B_REQ * SEQ * HID;             // 16.7M elements

  detect_k<<<1, 64, 0, stream>>>((const u16*)d_in[1], dflag);

#define BOTH(call_b, call_f) do { call_b; call_f; } while (0)
  BOTH((convert_k<u16>  <<<8192,256,0,stream>>>(dflag,0,(const u16*)  d_in[0], X_bf, NX)),
       (convert_k<float><<<8192,256,0,stream>>>(dflag,1,(const float*)d_in[0], X_bf, NX)));

  // A^T prep: ATqkv = {Aq,Ak,Av} x 4b (12 mats, slot1); ATo = Ao x 4b (4 mats, durable)
  BOTH((at_trans_k<u16>  <<<dim3(16,12),256,0,stream>>>(dflag,0,(const u16*)d_in[5],(const u16*)d_in[7],(const u16*)d_in[9],(const u16*)d_in[9],ATqkv)),
       (at_trans_k<float><<<dim3(16,12),256,0,stream>>>(dflag,1,(const float*)d_in[5],(const float*)d_in[7],(const float*)d_in[9],(const float*)d_in[9],ATqkv)));
  BOTH((at_trans_k<u16>  <<<dim3(16,4),256,0,stream>>>(dflag,0,(const u16*)d_in[11],(const u16*)d_in[11],(const u16*)d_in[11],(const u16*)d_in[11],ATo)),
       (at_trans_k<float><<<dim3(16,4),256,0,stream>>>(dflag,1,(const float*)d_in[11],(const float*)d_in[11],(const float*)d_in[11],(const float*)d_in[11],ATo)));

  lora_r_k<<<dim3(SEQ/16,B_REQ,3),256,0,stream>>>(X_bf, ATqkv, r_all);

  // QKV projections (k_lin write into slot1 happens after lora_r_k consumed ATqkv)
  u16* lin[3] = { q_lin, k_lin, v_lin };
  for (int m = 0; m < 3; m++) {
    BOTH((transpose_k<u16>  <<<dim3(64,64),256,0,stream>>>(dflag,0,(const u16*)  d_in[1+m], slot0)),
         (transpose_k<float><<<dim3(64,64),256,0,stream>>>(dflag,1,(const float*)d_in[1+m], slot0)));
    gemm256_k<u16><<<256,512,0,stream>>>(dflag,-1, X_bf, slot0, lin[m]);
  }
  BOTH((lora_rope_k<u16>  <<<dim3(SEQ/4,12),256,0,stream>>>(dflag,0,q_lin,k_lin,v_lin,r_all,(const u16*)d_in[6],(const u16*)d_in[8],(const u16*)d_in[10])),
       (lora_rope_k<float><<<dim3(SEQ/4,12),256,0,stream>>>(dflag,1,q_lin,k_lin,v_lin,r_all,(const float*)d_in[6],(const float*)d_in[8],(const float*)d_in[10])));

  // V^T into X_bf (hidden_states no longer needed)
  vtrans_k<<<dim3(SEQ/64,NH,B_REQ),256,0,stream>>>(v_lin, X_bf);

  attn_k<<<dim3(16,NH,B_REQ),256,0,stream>>>(q_lin, k_lin, X_bf, attnb);

  lora_r_k<<<dim3(SEQ/16,B_REQ,1),256,0,stream>>>(attnb, ATo, r_o);

  BOTH((transpose_k<u16>  <<<dim3(64,64),256,0,stream>>>(dflag,0,(const u16*)  d_in[4], slot1)),
       (transpose_k<float><<<dim3(64,64),256,0,stream>>>(dflag,1,(const float*)d_in[4], slot1)));
  BOTH((gemm256_k<u16>  <<<256,512,0,stream>>>(dflag,0, attnb, slot1, (u16*)d_out)),
       (gemm256_k<float><<<256,512,0,stream>>>(dflag,1, attnb, slot1, (float*)d_out)));
  BOTH((out_add_k<u16>  <<<dim3(16,SEQ,B_REQ),256,0,stream>>>(dflag,0,r_o,(const u16*)d_in[12],(u16*)d_out)),
       (out_add_k<float><<<dim3(16,SEQ,B_REQ),256,0,stream>>>(dflag,1,r_o,(const float*)d_in[12],(float*)d_out)));
#undef BOTH
}